// Round 6
// baseline (599.050 us; speedup 1.0000x reference)
//
#include <hip/hip_runtime.h>

#define SEMEME_SIZE 2048
#define D_MODEL 512
#define WAVES_PER_BLOCK 4
#define BLOCK (WAVES_PER_BLOCK * 64)

// clang native vectors — required by __builtin_nontemporal_{load,store}
typedef float vf4 __attribute__((ext_vector_type(4)));

// ============================ DIAGNOSTIC ROUND =============================
// R4's fused wave-per-token kernel, body repeated REPS times (idempotent:
// each rep recomputes from zero and overwrites the same output). Purpose:
//  (1) (dur_us - 342)/7 = per-rep kernel time -> separates kernel cost from
//      the ~250-310 us harness restore floor that dominates the headline.
//  (2) 8x body pushes the kernel above the 161 us top-5 profile cut so we
//      finally get its own FETCH_SIZE / hbm_gbps / VALUBusy row.
// The rep loop carries an asm memory clobber so the compiler cannot CSE the
// gather loads across reps.
// ===========================================================================
__global__ __launch_bounds__(BLOCK) void sememe_embed_kernel(
    const int* __restrict__ x,
    const float* __restrict__ w2s,
    const float* __restrict__ W,
    float* __restrict__ out,
    int n_tokens,
    int reps)
{
    const int wave = blockIdx.x * WAVES_PER_BLOCK + (threadIdx.x >> 6);
    const int lane = threadIdx.x & 63;
    if (wave >= n_tokens) return;

    const int wid = x[wave];  // wave-uniform
    const vf4* __restrict__ row4 = (const vf4*)(w2s + (size_t)wid * SEMEME_SIZE);
    const vf4* __restrict__ Wlo = (const vf4*)W + lane;        // dims lane*4..+3
    const vf4* __restrict__ Whi = (const vf4*)W + 64 + lane;   // dims 256+lane*4..+3
    vf4* __restrict__ o = (vf4*)(out + (size_t)wave * D_MODEL);

    #pragma unroll 1
    for (int rep = 0; rep < reps; ++rep) {
        __asm__ volatile("" ::: "memory");  // defeat cross-rep load CSE

        // ---- Phase 1: scan + ballot (pattern is 0/1-valued) --------------
        unsigned long long mask[8][4];
        #pragma unroll
        for (int c = 0; c < 8; ++c) {
            const vf4 v = __builtin_nontemporal_load(&row4[c * 64 + lane]);
            mask[c][0] = __ballot(v.x != 0.0f);
            mask[c][1] = __ballot(v.y != 0.0f);
            mask[c][2] = __ballot(v.z != 0.0f);
            mask[c][3] = __ballot(v.w != 0.0f);
        }

        // ---- Phase 2: scalar bit-walk, coalesced W accumulation ----------
        vf4 acc0 = {0.f, 0.f, 0.f, 0.f};
        vf4 acc1 = {0.f, 0.f, 0.f, 0.f};
        int count = 0;

        #pragma unroll
        for (int c = 0; c < 8; ++c) {
            #pragma unroll
            for (int j = 0; j < 4; ++j) {
                unsigned long long m = mask[c][j];
                count += __popcll(m);
                while (m) {
                    const int b = __ffsll((long long)m) - 1;
                    m &= m - 1;
                    const int k = c * 256 + b * 4 + j;
                    acc0 += Wlo[(size_t)k * (D_MODEL / 4)];
                    acc1 += Whi[(size_t)k * (D_MODEL / 4)];
                }
            }
        }

        const float scale = 22.62741699796952f / ((float)count + 1e-6f);
        acc0 *= scale;
        acc1 *= scale;

        __builtin_nontemporal_store(acc0, &o[lane]);
        __builtin_nontemporal_store(acc1, &o[lane + 64]);
    }
}

extern "C" void kernel_launch(void* const* d_in, const int* in_sizes, int n_in,
                              void* d_out, int out_size, void* d_ws, size_t ws_size,
                              hipStream_t stream) {
    const int*   x   = (const int*)d_in[0];     // [B*S] token ids
    const float* w2s = (const float*)d_in[1];   // [VOCAB, SEMEME_SIZE], values in {0,1}
    const float* W   = (const float*)d_in[2];   // [SEMEME_SIZE, D_MODEL]
    float* out = (float*)d_out;                 // [B*S, D_MODEL]

    const int n_tokens = in_sizes[0];           // 16384
    const int n_blocks = (n_tokens + WAVES_PER_BLOCK - 1) / WAVES_PER_BLOCK;

    sememe_embed_kernel<<<n_blocks, BLOCK, 0, stream>>>(x, w2s, W, out, n_tokens, /*reps=*/8);
}